// Round 2
// baseline (49777.838 us; speedup 1.0000x reference)
//
#include <hip/hip_runtime.h>

// 2-layer tanh RNN, B=32, T=1024, H=1024. Persistent producer-consumer kernel:
// WG 0..127 = layer 0, 128..255 = layer 1 (pipelined, lag ~1 step).
// Each WG owns a 16b x 16n output tile. Weights (Wh hi/lo, Wx hi/lo bf16) live
// in VGPRs for the whole kernel. Activations exchanged as bf16 hi+lo planes
// (near-fp32 accurate). Single LDS staging phase per step, XOR-swizzled.
#define BB 32
#define TT 1024
#define HH 1024
#define RING 128

typedef float f32x4 __attribute__((ext_vector_type(4)));
typedef short bf16x8 __attribute__((ext_vector_type(8)));
typedef unsigned short u16;

__device__ __forceinline__ u16 f2bf(float f) {
  unsigned u = __builtin_bit_cast(unsigned, f);
  u += 0x7fffu + ((u >> 16) & 1u);   // RNE
  return (u16)(u >> 16);
}
__device__ __forceinline__ float bf2f(u16 h) {
  return __builtin_bit_cast(float, (unsigned)h << 16);
}
__device__ __forceinline__ bf16x8 packhi(f32x4 a, f32x4 b) {
  bf16x8 r;
  r[0] = (short)f2bf(a[0]); r[1] = (short)f2bf(a[1]);
  r[2] = (short)f2bf(a[2]); r[3] = (short)f2bf(a[3]);
  r[4] = (short)f2bf(b[0]); r[5] = (short)f2bf(b[1]);
  r[6] = (short)f2bf(b[2]); r[7] = (short)f2bf(b[3]);
  return r;
}
__device__ __forceinline__ bf16x8 packlo(f32x4 a, f32x4 b, bf16x8 hi) {
  bf16x8 r;
  r[0] = (short)f2bf(a[0] - bf2f((u16)hi[0]));
  r[1] = (short)f2bf(a[1] - bf2f((u16)hi[1]));
  r[2] = (short)f2bf(a[2] - bf2f((u16)hi[2]));
  r[3] = (short)f2bf(a[3] - bf2f((u16)hi[3]));
  r[4] = (short)f2bf(b[0] - bf2f((u16)hi[4]));
  r[5] = (short)f2bf(b[1] - bf2f((u16)hi[5]));
  r[6] = (short)f2bf(b[2] - bf2f((u16)hi[6]));
  r[7] = (short)f2bf(b[3] - bf2f((u16)hi[7]));
  return r;
}
__device__ __forceinline__ void spinwait(const unsigned* p, unsigned tgt) {
  while (__hip_atomic_load(p, __ATOMIC_RELAXED, __HIP_MEMORY_SCOPE_AGENT) < tgt)
    __builtin_amdgcn_s_sleep(2);
}

// LDS 135,232 B -> 1 WG/CU guaranteed (>80 KiB), fits 160 KiB.
// abuf*: 16 rows x 2048 cols bf16, stored in 8-short blocks; logical block b of
// row r lives at phys block b^r -> all b128 LDS ops are <=2-way (free).
// Cols 0..1023 = recurrent-h, 1024..2047 = x-side (x for L0, h1 for L1).
struct Shm {
  u16   abufA[16][2048];  // hi plane
  u16   abufL[16][2048];  // lo plane
  float red[4][260];      // cross-wave K-partial tiles
};

__global__ __launch_bounds__(256, 1) void rnn_fused(
    const float* __restrict__ x, const float* __restrict__ Wx,
    const float* __restrict__ Wh, const float* __restrict__ bx,
    const float* __restrict__ bh, float* __restrict__ out,
    u16* __restrict__ ring,      // [RING][2][BB][HH] bf16 (hi,lo)
    u16* __restrict__ hbuf2,     // [2][2][BB][HH] bf16 ping-pong
    unsigned* __restrict__ flags)
{
  __shared__ Shm s;
  const int tid   = threadIdx.x;
  const int wg    = blockIdx.x;
  const int layer = wg >> 7;
  const int lwg   = wg & 127;
  const int n0    = (lwg & 63) << 4;
  const int b0    = (lwg >> 6) << 4;
  const int lane  = tid & 63;
  const int wv    = tid >> 6;         // wave = K-quarter
  const int am    = lane & 15;
  const int aq    = lane >> 4;

  // ---- one-time: weight B-fragments into VGPRs (hi/lo split) ----
  // lane (am,aq), wave wv holds W[n0+am][wv*256 + ss*32 + aq*8 .. +8]
  bf16x8 whHi[8], whLo[8], wxHi[8], wxLo[8];
  {
    const float* WhL = Wh + (size_t)layer * HH * HH + (size_t)(n0 + am) * HH + (wv << 8) + (aq << 3);
    const float* WxL = Wx + (size_t)layer * HH * HH + (size_t)(n0 + am) * HH + (wv << 8) + (aq << 3);
    #pragma unroll
    for (int ss = 0; ss < 8; ++ss) {
      f32x4 a = *(const f32x4*)(WhL + (ss << 5));
      f32x4 b = *(const f32x4*)(WhL + (ss << 5) + 4);
      whHi[ss] = packhi(a, b);
      whLo[ss] = packlo(a, b, whHi[ss]);
      f32x4 c = *(const f32x4*)(WxL + (ss << 5));
      f32x4 d = *(const f32x4*)(WxL + (ss << 5) + 4);
      wxHi[ss] = packhi(c, d);
      wxLo[ss] = packlo(c, d, wxHi[ss]);
    }
  }

  // epilogue mapping: thread tid owns tile element (row tid>>4, col tid&15)
  const int   colE   = n0 + (tid & 15);
  const int   rowE   = tid >> 4;
  const float biasv  = bx[layer * HH + colE] + bh[layer * HH + colE];
  const int   off_bh = (b0 + rowE) * HH + colE;
  const int   obase  = (b0 + rowE) * (TT * HH) + colE;

  const int SLOT = 2 * BB * HH;   // shorts per exchange slot (hi+lo planes)

  for (int t = 0; t < TT; ++t) {
    // ---- wait for producers (+ ring backpressure for L0) ----
    unsigned tgt;
    if (layer == 0)
      tgt = (tid < 128) ? (unsigned)t : (t >= RING ? (unsigned)(t - RING + 1) : 0u);
    else
      tgt = (tid < 128) ? (unsigned)(t + 1) : (unsigned)t;
    spinwait(&flags[tid], tgt);
    __syncthreads();
    __threadfence();   // acquire: discard stale cached exchange data

    // ---- single staging phase: recurrent-h (hi,lo) + x-side into LDS ----
    const u16* hs = (layer ? hbuf2 + (t & 1) * SLOT
                           : ring + ((t + RING - 1) & (RING - 1)) * SLOT) + b0 * HH;
    #pragma unroll
    for (int it = 0; it < 8; ++it) {            // h hi: 16x1024 bf16
      int idx = it * 256 + tid, r = idx >> 7, cb = idx & 127;
      f32x4 v = *(const f32x4*)(hs + r * HH + (cb << 3));
      *(f32x4*)(&s.abufA[r][(cb ^ r) << 3]) = v;
    }
    #pragma unroll
    for (int it = 0; it < 8; ++it) {            // h lo
      int idx = it * 256 + tid, r = idx >> 7, cb = idx & 127;
      f32x4 v = *(const f32x4*)(hs + BB * HH + r * HH + (cb << 3));
      *(f32x4*)(&s.abufL[r][(cb ^ r) << 3]) = v;
    }
    if (layer == 0) {
      // x fp32 -> hi/lo bf16 on the fly (x stays exact through hi+lo)
      #pragma unroll
      for (int it = 0; it < 8; ++it) {
        int idx = it * 256 + tid, r = idx >> 7, cb = idx & 127;
        const float* xs = x + (size_t)(b0 + r) * (TT * HH) + (size_t)t * HH + (cb << 3);
        f32x4 a = *(const f32x4*)xs;
        f32x4 b = *(const f32x4*)(xs + 4);
        bf16x8 hi = packhi(a, b);
        bf16x8 lo = packlo(a, b, hi);
        *(bf16x8*)(&s.abufA[r][(128 + (cb ^ r)) << 3]) = hi;
        *(bf16x8*)(&s.abufL[r][(128 + (cb ^ r)) << 3]) = lo;
      }
    } else {
      const u16* h1 = ring + (t & (RING - 1)) * SLOT + b0 * HH;
      #pragma unroll
      for (int it = 0; it < 8; ++it) {          // h1 hi
        int idx = it * 256 + tid, r = idx >> 7, cb = idx & 127;
        f32x4 v = *(const f32x4*)(h1 + r * HH + (cb << 3));
        *(f32x4*)(&s.abufA[r][(128 + (cb ^ r)) << 3]) = v;
      }
      #pragma unroll
      for (int it = 0; it < 8; ++it) {          // h1 lo
        int idx = it * 256 + tid, r = idx >> 7, cb = idx & 127;
        f32x4 v = *(const f32x4*)(h1 + BB * HH + r * HH + (cb << 3));
        *(f32x4*)(&s.abufL[r][(128 + (cb ^ r)) << 3]) = v;
      }
    }
    __syncthreads();

    // ---- MFMA: wave wv covers K-slice [wv*256, wv*256+256) of both halves ----
    f32x4 acc0 = {0.f,0.f,0.f,0.f}, acc1 = {0.f,0.f,0.f,0.f};
    f32x4 acc2 = {0.f,0.f,0.f,0.f}, acc3 = {0.f,0.f,0.f,0.f};
    #pragma unroll
    for (int ss = 0; ss < 8; ++ss) {
      const int blk = (wv << 5) + (ss << 2) + aq;       // logical block 0..127
      const int off = (blk ^ am) << 3;                  // swizzled col
      bf16x8 aH = *(const bf16x8*)(&s.abufA[am][off]);
      bf16x8 aL = *(const bf16x8*)(&s.abufL[am][off]);
      bf16x8 xH = *(const bf16x8*)(&s.abufA[am][off + 1024]);
      bf16x8 xL = *(const bf16x8*)(&s.abufL[am][off + 1024]);
      acc0 = __builtin_amdgcn_mfma_f32_16x16x32_bf16(aH, whHi[ss], acc0, 0, 0, 0);
      acc1 = __builtin_amdgcn_mfma_f32_16x16x32_bf16(aH, whLo[ss], acc1, 0, 0, 0);
      acc2 = __builtin_amdgcn_mfma_f32_16x16x32_bf16(aL, whHi[ss], acc2, 0, 0, 0);
      acc3 = __builtin_amdgcn_mfma_f32_16x16x32_bf16(xH, wxHi[ss], acc3, 0, 0, 0);
      acc0 = __builtin_amdgcn_mfma_f32_16x16x32_bf16(xH, wxLo[ss], acc0, 0, 0, 0);
      acc1 = __builtin_amdgcn_mfma_f32_16x16x32_bf16(xL, wxHi[ss], acc1, 0, 0, 0);
    }

    // ---- cross-wave K-reduce + epilogue ----
    f32x4 acc = (acc0 + acc1) + (acc2 + acc3);
    const int rbase = (aq << 6) + am;   // elem = (aq*4+i)*16 + am
    s.red[wv][rbase     ] = acc[0];
    s.red[wv][rbase + 16] = acc[1];
    s.red[wv][rbase + 32] = acc[2];
    s.red[wv][rbase + 48] = acc[3];
    __syncthreads();
    float v = s.red[0][tid] + s.red[1][tid] + s.red[2][tid] + s.red[3][tid] + biasv;
    float h = tanhf(v);

    u16 hb = f2bf(h);
    u16 hl = f2bf(h - bf2f(hb));
    u16* dst = layer ? (hbuf2 + ((t + 1) & 1) * SLOT)
                     : (ring + (t & (RING - 1)) * SLOT);
    dst[off_bh] = hb;
    dst[BB * HH + off_bh] = hl;
    if (layer) out[obase + t * HH] = h;                                   // [B,T,H]
    if (t == TT - 1) out[BB * TT * HH + layer * (BB * HH) + off_bh] = h;  // h_n [L,B,H]

    __threadfence();   // release: make h stores agent-visible before flag
    __syncthreads();
    if (tid == 0)
      __hip_atomic_store(&flags[wg], (unsigned)(t + 1),
                         __ATOMIC_RELEASE, __HIP_MEMORY_SCOPE_AGENT);
  }
}

// Zero the bits of workspace that are read before first write (harness poisons
// ws with 0xAA each launch): ring slot 127 (= h1_{-1}), both hbuf2 slots, flags.
__global__ void prep(u16* ring, u16* hbuf2, unsigned* flags) {
  int i = blockIdx.x * 256 + threadIdx.x;
  unsigned* z1 = (unsigned*)(ring + (size_t)127 * 2 * BB * HH);  // 32768 u32
  unsigned* z2 = (unsigned*)hbuf2;                               // 65536 u32
  if (i < 32768)            z1[i] = 0;
  else if (i < 32768+65536) z2[i - 32768] = 0;
  else if (i < 32768+65536+256) flags[i - 98304] = 0;
}

extern "C" void kernel_launch(void* const* d_in, const int* in_sizes, int n_in,
                              void* d_out, int out_size, void* d_ws, size_t ws_size,
                              hipStream_t stream) {
  const float* x  = (const float*)d_in[0];
  const float* Wx = (const float*)d_in[1];
  const float* Wh = (const float*)d_in[2];
  const float* bx = (const float*)d_in[3];
  const float* bh = (const float*)d_in[4];
  float* out = (float*)d_out;

  char* ws = (char*)d_ws;
  u16* ring = (u16*)ws;                                   // 128 slots x 128 KiB = 16.8 MB
  size_t off1 = (size_t)RING * 2 * BB * HH * sizeof(u16);
  u16* hbuf2 = (u16*)(ws + off1);                         // 256 KiB
  size_t off2 = off1 + (size_t)2 * 2 * BB * HH * sizeof(u16);
  unsigned* flags = (unsigned*)(ws + off2);               // 1 KiB

  prep<<<385, 256, 0, stream>>>(ring, hbuf2, flags);
  rnn_fused<<<256, 256, 0, stream>>>(x, Wx, Wh, bx, bh, out, ring, hbuf2, flags);
}

// Round 3
// 16974.471 us; speedup vs baseline: 2.9325x; 2.9325x over previous
//
#include <hip/hip_runtime.h>

// 2-layer tanh RNN, B=32, T=1024, H=1024. Persistent pipelined kernel.
// WG 0..127 = layer 0, 128..255 = layer 1. Each WG owns a 16b x 16n tile.
// Weights in VGPRs (Wh hi/lo, Wx hi/lo bf16). h exchanged as u32(hi|lo<<16)
// via write-through agent atomics (LLC-coherent, no L2 flush on release).
// Sync: per-(layer,bgroup,t) counters, one poller lane per dependency.
// MFMA A-fragments loaded directly from global (no LDS staging).
#define BB 32
#define TT 1024
#define HH 1024
#define RING 128

typedef float f32x4 __attribute__((ext_vector_type(4)));
typedef short bf16x8 __attribute__((ext_vector_type(8)));
typedef unsigned uint4v __attribute__((ext_vector_type(4)));
typedef unsigned short u16;

__device__ __forceinline__ u16 f2bf(float f) {
  unsigned u = __builtin_bit_cast(unsigned, f);
  u += 0x7fffu + ((u >> 16) & 1u);   // RNE
  return (u16)(u >> 16);
}
__device__ __forceinline__ float bf2f(u16 h) {
  return __builtin_bit_cast(float, (unsigned)h << 16);
}
__device__ __forceinline__ bf16x8 packhi(f32x4 a, f32x4 b) {
  bf16x8 r;
  r[0] = (short)f2bf(a[0]); r[1] = (short)f2bf(a[1]);
  r[2] = (short)f2bf(a[2]); r[3] = (short)f2bf(a[3]);
  r[4] = (short)f2bf(b[0]); r[5] = (short)f2bf(b[1]);
  r[6] = (short)f2bf(b[2]); r[7] = (short)f2bf(b[3]);
  return r;
}
__device__ __forceinline__ bf16x8 packlo(f32x4 a, f32x4 b, bf16x8 hi) {
  bf16x8 r;
  r[0] = (short)f2bf(a[0] - bf2f((u16)hi[0]));
  r[1] = (short)f2bf(a[1] - bf2f((u16)hi[1]));
  r[2] = (short)f2bf(a[2] - bf2f((u16)hi[2]));
  r[3] = (short)f2bf(a[3] - bf2f((u16)hi[3]));
  r[4] = (short)f2bf(b[0] - bf2f((u16)hi[4]));
  r[5] = (short)f2bf(b[1] - bf2f((u16)hi[5]));
  r[6] = (short)f2bf(b[2] - bf2f((u16)hi[6]));
  r[7] = (short)f2bf(b[3] - bf2f((u16)hi[7]));
  return r;
}
// merge low16 halves of 8 u32s (hi-bf16 plane) / high16 halves (lo plane)
__device__ __forceinline__ bf16x8 mergelo(uint4v q0, uint4v q1) {
  uint4v r;
  r.x = __builtin_amdgcn_perm(q0.y, q0.x, 0x05040100u);
  r.y = __builtin_amdgcn_perm(q0.w, q0.z, 0x05040100u);
  r.z = __builtin_amdgcn_perm(q1.y, q1.x, 0x05040100u);
  r.w = __builtin_amdgcn_perm(q1.w, q1.z, 0x05040100u);
  return __builtin_bit_cast(bf16x8, r);
}
__device__ __forceinline__ bf16x8 mergehi(uint4v q0, uint4v q1) {
  uint4v r;
  r.x = __builtin_amdgcn_perm(q0.y, q0.x, 0x07060302u);
  r.y = __builtin_amdgcn_perm(q0.w, q0.z, 0x07060302u);
  r.z = __builtin_amdgcn_perm(q1.y, q1.x, 0x07060302u);
  r.w = __builtin_amdgcn_perm(q1.w, q1.z, 0x07060302u);
  return __builtin_bit_cast(bf16x8, r);
}
__device__ __forceinline__ void spin(const unsigned* p, unsigned tgt) {
  while (__hip_atomic_load(p, __ATOMIC_RELAXED, __HIP_MEMORY_SCOPE_AGENT) < tgt)
    __builtin_amdgcn_s_sleep(1);
}
#define MFMA __builtin_amdgcn_mfma_f32_16x16x32_bf16

__global__ __launch_bounds__(256, 1) void rnn_fused(
    const float* __restrict__ x, const float* __restrict__ Wx,
    const float* __restrict__ Wh, const float* __restrict__ bx,
    const float* __restrict__ bh, float* __restrict__ out,
    unsigned* __restrict__ ring,   // [RING][BB][HH] u32 (hi|lo<<16)
    unsigned* __restrict__ hbuf2,  // [2][BB][HH] u32 ping-pong (layer-1 h)
    unsigned* __restrict__ cnt)    // [4][TT]: producers done (layer*2+bg, t)
{
  __shared__ float red[4][5200];   // 83.2 KB -> forces 1 WG/CU
  const int tid   = threadIdx.x;
  const int wg    = blockIdx.x;
  const int layer = wg >> 7;
  const int lwg   = wg & 127;
  const int n0    = (lwg & 63) << 4;
  const int b0    = (lwg >> 6) << 4;
  const int bg    = b0 >> 4;
  const int lane  = tid & 63;
  const int wv    = tid >> 6;          // wave = K-quarter (256 K each)
  const int am    = lane & 15;
  const int aq    = lane >> 4;
  const int fragoff = (wv << 8) + (aq << 3);

  // ---- one-time: weight B-fragments into VGPRs (hi/lo split) ----
  bf16x8 whHi[8], whLo[8], wxHi[8], wxLo[8];
  {
    const float* WhL = Wh + (size_t)layer * HH * HH + (size_t)(n0 + am) * HH + fragoff;
    const float* WxL = Wx + (size_t)layer * HH * HH + (size_t)(n0 + am) * HH + fragoff;
    #pragma unroll
    for (int ss = 0; ss < 8; ++ss) {
      f32x4 a = *(const f32x4*)(WhL + (ss << 5));
      f32x4 b = *(const f32x4*)(WhL + (ss << 5) + 4);
      whHi[ss] = packhi(a, b);
      whLo[ss] = packlo(a, b, whHi[ss]);
      f32x4 c = *(const f32x4*)(WxL + (ss << 5));
      f32x4 d = *(const f32x4*)(WxL + (ss << 5) + 4);
      wxHi[ss] = packhi(c, d);
      wxLo[ss] = packlo(c, d, wxHi[ss]);
    }
  }

  // epilogue mapping: thread tid owns tile element (row tid>>4, col tid&15)
  const int   colE   = n0 + (tid & 15);
  const int   rowE   = tid >> 4;
  const float biasv  = bx[layer * HH + colE] + bh[layer * HH + colE];
  const int   off_bh = (b0 + rowE) * HH + colE;
  const int   obase  = (b0 + rowE) * (TT * HH) + colE;

  // layer-0: x fragments for step t prefetched during the previous step's wait
  bf16x8 xH[8], xL[8];
  if (layer == 0) {
    const float* xp = x + (size_t)(b0 + am) * (TT * HH) + fragoff;  // t = 0
    #pragma unroll
    for (int ss = 0; ss < 8; ++ss) {
      f32x4 a = *(const f32x4*)(xp + (ss << 5));
      f32x4 b = *(const f32x4*)(xp + (ss << 5) + 4);
      xH[ss] = packhi(a, b);
      xL[ss] = packlo(a, b, xH[ss]);
    }
  }

  for (int t = 0; t < TT; ++t) {
    // ---- wait for producers: one poller lane per dependency ----
    if (layer == 0) {
      if (tid == 0  && t >= 1)    spin(cnt + bg * TT + (t - 1), 64);          // own layer t-1
      if (tid == 64 && t >= RING) spin(cnt + (2 + bg) * TT + (t - RING), 64); // ring backpressure
    } else {
      if (tid == 0)               spin(cnt + bg * TT + t, 64);                // L0 output t
      if (tid == 64 && t >= 1)    spin(cnt + (2 + bg) * TT + (t - 1), 64);    // own layer t-1
    }
    __syncthreads();
    __builtin_amdgcn_fence(__ATOMIC_ACQUIRE, "agent");   // buffer_inv, no wbl2

    f32x4 acc0 = {0.f,0.f,0.f,0.f}, acc1 = {0.f,0.f,0.f,0.f};
    f32x4 acc2 = {0.f,0.f,0.f,0.f}, acc3 = {0.f,0.f,0.f,0.f};

    if (layer == 0) {
      const unsigned* hp = ring + (size_t)((t + RING - 1) & (RING - 1)) * (BB * HH)
                         + (b0 + am) * HH + fragoff;
      #pragma unroll
      for (int ss = 0; ss < 8; ++ss) {
        uint4v q0 = *(const uint4v*)(hp + (ss << 5));
        uint4v q1 = *(const uint4v*)(hp + (ss << 5) + 4);
        bf16x8 aH = mergelo(q0, q1);
        bf16x8 aL = mergehi(q0, q1);
        acc0 = MFMA(aH, whHi[ss], acc0, 0, 0, 0);
        acc1 = MFMA(aH, whLo[ss], acc1, 0, 0, 0);
        acc2 = MFMA(aL, whHi[ss], acc2, 0, 0, 0);
        acc3 = MFMA(xH[ss], wxHi[ss], acc3, 0, 0, 0);
        acc0 = MFMA(xH[ss], wxLo[ss], acc0, 0, 0, 0);
        acc1 = MFMA(xL[ss], wxHi[ss], acc1, 0, 0, 0);
      }
    } else {
      const unsigned* hp = hbuf2 + (size_t)(t & 1) * (BB * HH) + (b0 + am) * HH + fragoff;
      const unsigned* rp = ring + (size_t)(t & (RING - 1)) * (BB * HH) + (b0 + am) * HH + fragoff;
      #pragma unroll
      for (int ss = 0; ss < 8; ++ss) {
        uint4v q0 = *(const uint4v*)(hp + (ss << 5));
        uint4v q1 = *(const uint4v*)(hp + (ss << 5) + 4);
        uint4v r0 = *(const uint4v*)(rp + (ss << 5));
        uint4v r1 = *(const uint4v*)(rp + (ss << 5) + 4);
        bf16x8 aH = mergelo(q0, q1);
        bf16x8 aL = mergehi(q0, q1);
        bf16x8 gH = mergelo(r0, r1);
        bf16x8 gL = mergehi(r0, r1);
        acc0 = MFMA(aH, whHi[ss], acc0, 0, 0, 0);
        acc1 = MFMA(aH, whLo[ss], acc1, 0, 0, 0);
        acc2 = MFMA(aL, whHi[ss], acc2, 0, 0, 0);
        acc3 = MFMA(gH, wxHi[ss], acc3, 0, 0, 0);
        acc0 = MFMA(gH, wxLo[ss], acc0, 0, 0, 0);
        acc1 = MFMA(gL, wxHi[ss], acc1, 0, 0, 0);
      }
    }

    // ---- cross-wave K-reduce + epilogue ----
    f32x4 acc = (acc0 + acc1) + (acc2 + acc3);
    const int rbase = (aq << 6) + am;       // elem = (aq*4+i)*16 + am
    red[wv][rbase     ] = acc[0];
    red[wv][rbase + 16] = acc[1];
    red[wv][rbase + 32] = acc[2];
    red[wv][rbase + 48] = acc[3];
    __syncthreads();
    float v = red[0][tid] + red[1][tid] + red[2][tid] + red[3][tid] + biasv;
    float h = tanhf(v);

    // write-through exchange store (LLC-coherent; no dirty L2)
    unsigned pk = (unsigned)f2bf(h);
    pk |= (unsigned)f2bf(h - bf2f((u16)pk)) << 16;
    unsigned* dst = layer ? hbuf2 + (size_t)((t + 1) & 1) * (BB * HH)
                          : ring + (size_t)(t & (RING - 1)) * (BB * HH);
    __hip_atomic_store(&dst[off_bh], pk, __ATOMIC_RELAXED, __HIP_MEMORY_SCOPE_AGENT);
    __syncthreads();   // drains every wave's vmcnt -> stores are LLC-visible
    if (tid == 0)
      __hip_atomic_fetch_add(cnt + (layer * 2 + bg) * TT + t, 1u,
                             __ATOMIC_RELEASE, __HIP_MEMORY_SCOPE_AGENT);

    // off-critical-path work after publishing:
    if (layer) out[obase + t * HH] = h;                                    // [B,T,H]
    if (t == TT - 1) out[BB * TT * HH + layer * (BB * HH) + off_bh] = h;   // h_n [L,B,H]
    if (layer == 0 && t + 1 < TT) {
      const float* xp = x + (size_t)(b0 + am) * (TT * HH) + (size_t)(t + 1) * HH + fragoff;
      #pragma unroll
      for (int ss = 0; ss < 8; ++ss) {
        f32x4 a = *(const f32x4*)(xp + (ss << 5));
        f32x4 b = *(const f32x4*)(xp + (ss << 5) + 4);
        xH[ss] = packhi(a, b);
        xL[ss] = packlo(a, b, xH[ss]);
      }
    }
  }
}

// Zero what is read before first write (harness poisons ws with 0xAA):
// ring slot RING-1 (h0_{-1}=0), hbuf2 slot 0 (h1_{-1}=0), cnt[4][TT].
__global__ void prep(unsigned* ring, unsigned* hbuf2, unsigned* cnt) {
  int i = blockIdx.x * 256 + threadIdx.x;
  if (i < BB * HH)                       ring[(size_t)(RING - 1) * (BB * HH) + i] = 0;
  else if (i < 2 * BB * HH)              hbuf2[i - BB * HH] = 0;
  else if (i < 2 * BB * HH + 4 * TT)     cnt[i - 2 * BB * HH] = 0;
}

extern "C" void kernel_launch(void* const* d_in, const int* in_sizes, int n_in,
                              void* d_out, int out_size, void* d_ws, size_t ws_size,
                              hipStream_t stream) {
  const float* x  = (const float*)d_in[0];
  const float* Wx = (const float*)d_in[1];
  const float* Wh = (const float*)d_in[2];
  const float* bx = (const float*)d_in[3];
  const float* bh = (const float*)d_in[4];
  float* out = (float*)d_out;

  char* ws = (char*)d_ws;
  unsigned* ring = (unsigned*)ws;                              // 128 x 128 KiB = 16.8 MB
  size_t off1 = (size_t)RING * BB * HH * sizeof(unsigned);
  unsigned* hbuf2 = (unsigned*)(ws + off1);                    // 256 KiB
  size_t off2 = off1 + (size_t)2 * BB * HH * sizeof(unsigned);
  unsigned* cnt = (unsigned*)(ws + off2);                      // 16 KiB

  prep<<<272, 256, 0, stream>>>(ring, hbuf2, cnt);
  rnn_fused<<<256, 256, 0, stream>>>(x, Wx, Wh, bx, bh, out, ring, hbuf2, cnt);
}